// Round 1
// baseline (184.659 us; speedup 1.0000x reference)
//
#include <hip/hip_runtime.h>

// GNNEncoder fused MFMA kernel (round 3: barrier-free loop, 4 blocks/CU).
// B=16, S=2048, N=64, HD=32.
// Key changes vs round 2:
//  - SCHUNK 64->32: grid 512->1024 blocks (4 blocks/CU available, was 2).
//  - TCH 8->4 (one s-row per wave per iter): catg LDS 40->18 KB, total 27 KB.
//  - xs LDS + all in-loop __syncthreads deleted: x rows are wave-private,
//    read directly from global (L2-resident); catg slices are wave-private.
//  - __launch_bounds__(256,4): VGPR 108 fits 4 waves/SIMD.
//  - CATP 40->36: dword stride 18 (gcd(18,32)=2) => 2-way (free) LDS access
//    instead of 4-8-way; reads as 2x aligned b64.
#define BN 16
#define SN 2048
#define NV 64
#define HD 32
#define TCH 4               // s-rows per iteration (1 per wave)
#define SCHUNK 32           // s per block
#define NSUB (SCHUNK / TCH) // 8
#define CATP 36             // padded f-dim of agg LDS (72 B rows, stride 18 dwords)

typedef short  bf8_t  __attribute__((ext_vector_type(8)));   // raw-bit view for builtin
typedef __bf16 bfv8   __attribute__((ext_vector_type(8)));
typedef __bf16 bfv4   __attribute__((ext_vector_type(4)));
typedef float  f32x16 __attribute__((ext_vector_type(16)));

#define MFMA32(a, b, c) __builtin_amdgcn_mfma_f32_32x32x16_bf16( \
    __builtin_bit_cast(bf8_t, (a)), __builtin_bit_cast(bf8_t, (b)), (c), 0, 0, 0)

__global__ __launch_bounds__(256, 4) void gnn_mfma(
    const float* __restrict__ x,    // [B,S,N]
    const float* __restrict__ adj,  // [N,N]
    const float* __restrict__ w1,   // [HD]
    const float* __restrict__ b1,   // [HD]
    const float* __restrict__ w2,   // [HD, 2*HD]
    const float* __restrict__ b2,   // [HD]
    float* __restrict__ out)        // [B, N*HD]
{
    __shared__ __bf16 catg[TCH][NV][CATP];  // 18 KB, wave-private slices by wave id
    __shared__ float  red[NV * HD];         // 8 KB
    __shared__ float  rs[NV];

    const int tid  = threadIdx.x;
    const int w    = tid >> 6;
    const int lane = tid & 63;
    const int l31  = lane & 31;
    const int lh   = lane >> 5;             // 0/1 half-wave
    const int b    = blockIdx.x >> 6;       // 64 chunks per batch row
    const int chk  = blockIdx.x & 63;
    const int sbase = chk * SCHUNK;

    // zero the block reduce buffer
    #pragma unroll
    for (int q = 0; q < (NV * HD) / 256; ++q) red[tid + q * 256] = 0.f;

    // adjacency row inverse sums
    if (tid < NV) {
        float s = 0.f;
        const float4* r4 = (const float4*)(adj + tid * NV);
        #pragma unroll
        for (int q = 0; q < NV / 4; ++q) { float4 v = r4[q]; s += v.x + v.y + v.z + v.w; }
        rs[tid] = 1.f / (s + 1e-8f);
    }
    __syncthreads();   // the ONLY pre-epilogue barrier (rs + red-zero visibility)

    // --- An B-fragments (GEMM1), held in registers for the whole block ---
    // B[k=j][n=i]: lane -> n = nt*32+l31, k = kk*16 + lh*8 + e  => An[i][j] row-major
    bfv8 an[2][4];
    #pragma unroll
    for (int nt = 0; nt < 2; ++nt) {
        const int i = nt * 32 + l31;
        const float rsi = rs[i];
        #pragma unroll
        for (int kk = 0; kk < 4; ++kk) {
            const int j0 = kk * 16 + lh * 8;
            const float4 a0 = *(const float4*)(adj + i * NV + j0);
            const float4 a1 = *(const float4*)(adj + i * NV + j0 + 4);
            bfv8 v;
            v[0] = (__bf16)(a0.x * rsi); v[1] = (__bf16)(a0.y * rsi);
            v[2] = (__bf16)(a0.z * rsi); v[3] = (__bf16)(a0.w * rsi);
            v[4] = (__bf16)(a1.x * rsi); v[5] = (__bf16)(a1.y * rsi);
            v[6] = (__bf16)(a1.z * rsi); v[7] = (__bf16)(a1.w * rsi);
            an[nt][kk] = v;
        }
    }

    // --- W2^T B-fragments (GEMM2) ---
    // B[k][n=f']: lane -> f' = l31, k = kk*16 + lh*8 + e => w2[f'][k]
    bfv8 wf[4];
    #pragma unroll
    for (int kk = 0; kk < 4; ++kk) {
        const int k0 = kk * 16 + lh * 8;
        const float4 a0 = *(const float4*)(w2 + l31 * (2 * HD) + k0);
        const float4 a1 = *(const float4*)(w2 + l31 * (2 * HD) + k0 + 4);
        bfv8 v;
        v[0] = (__bf16)a0.x; v[1] = (__bf16)a0.y; v[2] = (__bf16)a0.z; v[3] = (__bf16)a0.w;
        v[4] = (__bf16)a1.x; v[5] = (__bf16)a1.y; v[6] = (__bf16)a1.z; v[7] = (__bf16)a1.w;
        wf[kk] = v;
    }

    // per-lane fc1/fc2 constants
    const float w1f = w1[l31];
    const float b1f = b1[l31];
    const float b2f = b2[l31];
    float w1k[2][8], b1k[2][8];
    #pragma unroll
    for (int kk = 0; kk < 2; ++kk) {
        const int k0 = kk * 16 + lh * 8;
        #pragma unroll
        for (int e = 0; e < 8; ++e) { w1k[kk][e] = w1[k0 + e]; b1k[kk][e] = b1[k0 + e]; }
    }

    f32x16 macc0, macc1;   // mean accumulators, ihalf = 0 / 1
    #pragma unroll
    for (int r = 0; r < 16; ++r) { macc0[r] = 0.f; macc1[r] = 0.f; }

    for (int t = 0; t < NSUB; ++t) {
        // this wave's s-row for this iteration (wave-private; no barriers needed)
        const float* xp = x + ((size_t)b * SN + sbase + t * TCH + w) * (size_t)NV;

        // ---- Phase 1: GEMM1 -> aggT, written to catg[w] (wave-private slice) ----
        bfv8 a1f[4];
        #pragma unroll
        for (int kk = 0; kk < 4; ++kk) {
            const int j0 = kk * 16 + lh * 8;
            const float4 xa = *(const float4*)(xp + j0);
            const float4 xb = *(const float4*)(xp + j0 + 4);
            bfv8 v;
            v[0] = (__bf16)fmaxf(xa.x * w1f + b1f, 0.f);
            v[1] = (__bf16)fmaxf(xa.y * w1f + b1f, 0.f);
            v[2] = (__bf16)fmaxf(xa.z * w1f + b1f, 0.f);
            v[3] = (__bf16)fmaxf(xa.w * w1f + b1f, 0.f);
            v[4] = (__bf16)fmaxf(xb.x * w1f + b1f, 0.f);
            v[5] = (__bf16)fmaxf(xb.y * w1f + b1f, 0.f);
            v[6] = (__bf16)fmaxf(xb.z * w1f + b1f, 0.f);
            v[7] = (__bf16)fmaxf(xb.w * w1f + b1f, 0.f);
            a1f[kk] = v;
        }
        #pragma unroll
        for (int nt = 0; nt < 2; ++nt) {
            f32x16 c;
            #pragma unroll
            for (int r = 0; r < 16; ++r) c[r] = 0.f;
            #pragma unroll
            for (int kk = 0; kk < 4; ++kk) c = MFMA32(a1f[kk], an[nt][kk], c);
            // C[m=f][n=i]: col=l31 -> i, row=(reg&3)+8*(reg>>2)+4*lh -> f
            const int i = nt * 32 + l31;
            #pragma unroll
            for (int g = 0; g < 4; ++g) {
                const int f0 = g * 8 + 4 * lh;
                bfv4 pv;
                pv[0] = (__bf16)c[g * 4 + 0]; pv[1] = (__bf16)c[g * 4 + 1];
                pv[2] = (__bf16)c[g * 4 + 2]; pv[3] = (__bf16)c[g * 4 + 3];
                *(bfv4*)&catg[w][i][f0] = pv;
            }
        }

        // ---- Phase 2: GEMM2 (same-wave catg slice; compiler orders ds ops) ----
        #pragma unroll
        for (int p = 0; p < 2; ++p) {
            const int ih = p;
            const int i  = ih * 32 + l31;
            const float xv = xp[i];
            f32x16 c;
            #pragma unroll
            for (int r = 0; r < 16; ++r) c[r] = 0.f;
            #pragma unroll
            for (int kk = 0; kk < 2; ++kk) {   // h part, k in [0,32)
                bfv8 v;
                #pragma unroll
                for (int e = 0; e < 8; ++e)
                    v[e] = (__bf16)fmaxf(xv * w1k[kk][e] + b1k[kk][e], 0.f);
                c = MFMA32(v, wf[kk], c);
            }
            #pragma unroll
            for (int kk = 2; kk < 4; ++kk) {   // agg part, k in [32,64)
                const int f0 = (kk - 2) * 16 + lh * 8;
                const bfv4 lo = *(const bfv4*)&catg[w][i][f0];
                const bfv4 hi = *(const bfv4*)&catg[w][i][f0 + 4];
                bfv8 v;
                #pragma unroll
                for (int e = 0; e < 4; ++e) { v[e] = lo[e]; v[e + 4] = hi[e]; }
                c = MFMA32(v, wf[kk], c);
            }
            #pragma unroll
            for (int r = 0; r < 16; ++r) {
                const float h2 = fmaxf(c[r] + b2f, 0.f);
                if (p == 0) macc0[r] += h2; else macc1[r] += h2;
            }
        }
    }

    // ---- epilogue: cross-wave reduce in LDS, then global atomics ----
    #pragma unroll
    for (int r = 0; r < 16; ++r) {
        const int row = (r & 3) + 8 * (r >> 2) + 4 * lh;  // i within half
        atomicAdd(&red[row * HD + l31], macc0[r]);
        atomicAdd(&red[(row + 32) * HD + l31], macc1[r]);
    }
    __syncthreads();
    const float inv = 1.f / (float)SN;
    #pragma unroll
    for (int q = 0; q < (NV * HD) / 256; ++q) {
        const int e = tid + q * 256;
        atomicAdd(out + (size_t)b * (NV * HD) + e, red[e] * inv);
    }
}

extern "C" void kernel_launch(void* const* d_in, const int* in_sizes, int n_in,
                              void* d_out, int out_size, void* d_ws, size_t ws_size,
                              hipStream_t stream) {
    const float* x   = (const float*)d_in[0];
    const float* adj = (const float*)d_in[1];
    const float* w1  = (const float*)d_in[2];
    const float* b1  = (const float*)d_in[3];
    const float* w2  = (const float*)d_in[4];
    const float* b2  = (const float*)d_in[5];
    float* out = (float*)d_out;

    hipMemsetAsync(out, 0, (size_t)out_size * sizeof(float), stream);
    gnn_mfma<<<dim3(BN * 64), dim3(256), 0, stream>>>(x, adj, w1, b1, w2, b2, out);
}

// Round 2
// 142.298 us; speedup vs baseline: 1.2977x; 1.2977x over previous
//
#include <hip/hip_runtime.h>

// GNNEncoder fused MFMA kernel (round 4: un-spill).
// B=16, S=2048, N=64, HD=32.
// Round-3 post-mortem: __launch_bounds__(256,4) forced the allocator to a
// 64-VGPR target while ~100 VGPRs of fragments/accumulators are loop-live
// -> scratch spills -> FETCH_SIZE 140 MB, WRITE_SIZE 50 MB, 2x regression.
// Fix: launch_bounds(256,2) (occupancy FLOOR, not residency cap). At ~108
// VGPR the HW still packs 4 waves/SIMD (512/108 -> 4) and LDS 27 KB allows
// 5 blocks/CU, so we keep round-3's ~40% occupancy without spilling.
#define BN 16
#define SN 2048
#define NV 64
#define HD 32
#define TCH 4               // s-rows per iteration (1 per wave)
#define SCHUNK 32           // s per block
#define NSUB (SCHUNK / TCH) // 8
#define CATP 36             // padded f-dim of agg LDS (72 B rows, stride 18 dwords)

typedef short  bf8_t  __attribute__((ext_vector_type(8)));   // raw-bit view for builtin
typedef __bf16 bfv8   __attribute__((ext_vector_type(8)));
typedef __bf16 bfv4   __attribute__((ext_vector_type(4)));
typedef float  f32x16 __attribute__((ext_vector_type(16)));

#define MFMA32(a, b, c) __builtin_amdgcn_mfma_f32_32x32x16_bf16( \
    __builtin_bit_cast(bf8_t, (a)), __builtin_bit_cast(bf8_t, (b)), (c), 0, 0, 0)

__global__ __launch_bounds__(256, 2) void gnn_mfma(
    const float* __restrict__ x,    // [B,S,N]
    const float* __restrict__ adj,  // [N,N]
    const float* __restrict__ w1,   // [HD]
    const float* __restrict__ b1,   // [HD]
    const float* __restrict__ w2,   // [HD, 2*HD]
    const float* __restrict__ b2,   // [HD]
    float* __restrict__ out)        // [B, N*HD]
{
    __shared__ __bf16 catg[TCH][NV][CATP];  // 18 KB, wave-private slices by wave id
    __shared__ float  red[NV * HD];         // 8 KB
    __shared__ float  rs[NV];

    const int tid  = threadIdx.x;
    const int w    = tid >> 6;
    const int lane = tid & 63;
    const int l31  = lane & 31;
    const int lh   = lane >> 5;             // 0/1 half-wave
    const int b    = blockIdx.x >> 6;       // 64 chunks per batch row
    const int chk  = blockIdx.x & 63;
    const int sbase = chk * SCHUNK;

    // zero the block reduce buffer
    #pragma unroll
    for (int q = 0; q < (NV * HD) / 256; ++q) red[tid + q * 256] = 0.f;

    // adjacency row inverse sums
    if (tid < NV) {
        float s = 0.f;
        const float4* r4 = (const float4*)(adj + tid * NV);
        #pragma unroll
        for (int q = 0; q < NV / 4; ++q) { float4 v = r4[q]; s += v.x + v.y + v.z + v.w; }
        rs[tid] = 1.f / (s + 1e-8f);
    }
    __syncthreads();   // the ONLY pre-epilogue barrier (rs + red-zero visibility)

    // --- An B-fragments (GEMM1), held in registers for the whole block ---
    // B[k=j][n=i]: lane -> n = nt*32+l31, k = kk*16 + lh*8 + e  => An[i][j] row-major
    bfv8 an[2][4];
    #pragma unroll
    for (int nt = 0; nt < 2; ++nt) {
        const int i = nt * 32 + l31;
        const float rsi = rs[i];
        #pragma unroll
        for (int kk = 0; kk < 4; ++kk) {
            const int j0 = kk * 16 + lh * 8;
            const float4 a0 = *(const float4*)(adj + i * NV + j0);
            const float4 a1 = *(const float4*)(adj + i * NV + j0 + 4);
            bfv8 v;
            v[0] = (__bf16)(a0.x * rsi); v[1] = (__bf16)(a0.y * rsi);
            v[2] = (__bf16)(a0.z * rsi); v[3] = (__bf16)(a0.w * rsi);
            v[4] = (__bf16)(a1.x * rsi); v[5] = (__bf16)(a1.y * rsi);
            v[6] = (__bf16)(a1.z * rsi); v[7] = (__bf16)(a1.w * rsi);
            an[nt][kk] = v;
        }
    }

    // --- W2^T B-fragments (GEMM2) ---
    // B[k][n=f']: lane -> f' = l31, k = kk*16 + lh*8 + e => w2[f'][k]
    bfv8 wf[4];
    #pragma unroll
    for (int kk = 0; kk < 4; ++kk) {
        const int k0 = kk * 16 + lh * 8;
        const float4 a0 = *(const float4*)(w2 + l31 * (2 * HD) + k0);
        const float4 a1 = *(const float4*)(w2 + l31 * (2 * HD) + k0 + 4);
        bfv8 v;
        v[0] = (__bf16)a0.x; v[1] = (__bf16)a0.y; v[2] = (__bf16)a0.z; v[3] = (__bf16)a0.w;
        v[4] = (__bf16)a1.x; v[5] = (__bf16)a1.y; v[6] = (__bf16)a1.z; v[7] = (__bf16)a1.w;
        wf[kk] = v;
    }

    // per-lane fc1/fc2 constants
    const float w1f = w1[l31];
    const float b1f = b1[l31];
    const float b2f = b2[l31];
    float w1k[2][8], b1k[2][8];
    #pragma unroll
    for (int kk = 0; kk < 2; ++kk) {
        const int k0 = kk * 16 + lh * 8;
        #pragma unroll
        for (int e = 0; e < 8; ++e) { w1k[kk][e] = w1[k0 + e]; b1k[kk][e] = b1[k0 + e]; }
    }

    f32x16 macc0, macc1;   // mean accumulators, ihalf = 0 / 1
    #pragma unroll
    for (int r = 0; r < 16; ++r) { macc0[r] = 0.f; macc1[r] = 0.f; }

    for (int t = 0; t < NSUB; ++t) {
        // this wave's s-row for this iteration (wave-private; no barriers needed)
        const float* xp = x + ((size_t)b * SN + sbase + t * TCH + w) * (size_t)NV;

        // ---- Phase 1: GEMM1 -> aggT, written to catg[w] (wave-private slice) ----
        bfv8 a1f[4];
        #pragma unroll
        for (int kk = 0; kk < 4; ++kk) {
            const int j0 = kk * 16 + lh * 8;
            const float4 xa = *(const float4*)(xp + j0);
            const float4 xb = *(const float4*)(xp + j0 + 4);
            bfv8 v;
            v[0] = (__bf16)fmaxf(xa.x * w1f + b1f, 0.f);
            v[1] = (__bf16)fmaxf(xa.y * w1f + b1f, 0.f);
            v[2] = (__bf16)fmaxf(xa.z * w1f + b1f, 0.f);
            v[3] = (__bf16)fmaxf(xa.w * w1f + b1f, 0.f);
            v[4] = (__bf16)fmaxf(xb.x * w1f + b1f, 0.f);
            v[5] = (__bf16)fmaxf(xb.y * w1f + b1f, 0.f);
            v[6] = (__bf16)fmaxf(xb.z * w1f + b1f, 0.f);
            v[7] = (__bf16)fmaxf(xb.w * w1f + b1f, 0.f);
            a1f[kk] = v;
        }
        #pragma unroll
        for (int nt = 0; nt < 2; ++nt) {
            f32x16 c;
            #pragma unroll
            for (int r = 0; r < 16; ++r) c[r] = 0.f;
            #pragma unroll
            for (int kk = 0; kk < 4; ++kk) c = MFMA32(a1f[kk], an[nt][kk], c);
            // C[m=f][n=i]: col=l31 -> i, row=(reg&3)+8*(reg>>2)+4*lh -> f
            const int i = nt * 32 + l31;
            #pragma unroll
            for (int g = 0; g < 4; ++g) {
                const int f0 = g * 8 + 4 * lh;
                bfv4 pv;
                pv[0] = (__bf16)c[g * 4 + 0]; pv[1] = (__bf16)c[g * 4 + 1];
                pv[2] = (__bf16)c[g * 4 + 2]; pv[3] = (__bf16)c[g * 4 + 3];
                *(bfv4*)&catg[w][i][f0] = pv;
            }
        }

        // ---- Phase 2: GEMM2 (same-wave catg slice; compiler orders ds ops) ----
        #pragma unroll
        for (int p = 0; p < 2; ++p) {
            const int ih = p;
            const int i  = ih * 32 + l31;
            const float xv = xp[i];
            f32x16 c;
            #pragma unroll
            for (int r = 0; r < 16; ++r) c[r] = 0.f;
            #pragma unroll
            for (int kk = 0; kk < 2; ++kk) {   // h part, k in [0,32)
                bfv8 v;
                #pragma unroll
                for (int e = 0; e < 8; ++e)
                    v[e] = (__bf16)fmaxf(xv * w1k[kk][e] + b1k[kk][e], 0.f);
                c = MFMA32(v, wf[kk], c);
            }
            #pragma unroll
            for (int kk = 2; kk < 4; ++kk) {   // agg part, k in [32,64)
                const int f0 = (kk - 2) * 16 + lh * 8;
                const bfv4 lo = *(const bfv4*)&catg[w][i][f0];
                const bfv4 hi = *(const bfv4*)&catg[w][i][f0 + 4];
                bfv8 v;
                #pragma unroll
                for (int e = 0; e < 4; ++e) { v[e] = lo[e]; v[e + 4] = hi[e]; }
                c = MFMA32(v, wf[kk], c);
            }
            #pragma unroll
            for (int r = 0; r < 16; ++r) {
                const float h2 = fmaxf(c[r] + b2f, 0.f);
                if (p == 0) macc0[r] += h2; else macc1[r] += h2;
            }
        }
    }

    // ---- epilogue: cross-wave reduce in LDS, then global atomics ----
    #pragma unroll
    for (int r = 0; r < 16; ++r) {
        const int row = (r & 3) + 8 * (r >> 2) + 4 * lh;  // i within half
        atomicAdd(&red[row * HD + l31], macc0[r]);
        atomicAdd(&red[(row + 32) * HD + l31], macc1[r]);
    }
    __syncthreads();
    const float inv = 1.f / (float)SN;
    #pragma unroll
    for (int q = 0; q < (NV * HD) / 256; ++q) {
        const int e = tid + q * 256;
        atomicAdd(out + (size_t)b * (NV * HD) + e, red[e] * inv);
    }
}

extern "C" void kernel_launch(void* const* d_in, const int* in_sizes, int n_in,
                              void* d_out, int out_size, void* d_ws, size_t ws_size,
                              hipStream_t stream) {
    const float* x   = (const float*)d_in[0];
    const float* adj = (const float*)d_in[1];
    const float* w1  = (const float*)d_in[2];
    const float* b1  = (const float*)d_in[3];
    const float* w2  = (const float*)d_in[4];
    const float* b2  = (const float*)d_in[5];
    float* out = (float*)d_out;

    hipMemsetAsync(out, 0, (size_t)out_size * sizeof(float), stream);
    gnn_mfma<<<dim3(BN * 64), dim3(256), 0, stream>>>(x, adj, w1, b1, w2, b2, out);
}